// Round 1
// baseline (363.739 us; speedup 1.0000x reference)
//
#include <hip/hip_runtime.h>
#include <math.h>

// Problem constants (match reference)
#define B_    32
#define L_    4096
#define D_    512
#define NST   64
#define UNITS 512
#define ROWS  (B_ * L_)          // 131072
#define PI_F  3.14159265358979323846f

// ---------------- workspace layout (bytes) ----------------
// total ~68.7 MB
#define OFF_WPK   ((size_t)0)
#define OFF_PSW   (OFF_WPK   + (size_t)512 * 128 * 4)        // packed [512][128] phi weights
#define OFF_ZPHI  (OFF_PSW   + (size_t)512 * 2 * 4)          // packed [512][2] psi weights
#define OFF_ZPSI  (OFF_ZPHI  + (size_t)ROWS * 128 * 4)       // z phi [ROWS][128]
#define OFF_PMPHI (OFF_ZPSI  + (size_t)ROWS * 2 * 4)         // z psi [ROWS][2]
#define OFF_PSPHI (OFF_PMPHI + (size_t)32 * 8 * 64 * 4)
#define OFF_PMPSI (OFF_PSPHI + (size_t)32 * 8 * 64 * 4)
#define OFF_PSPSI (OFF_PMPSI + (size_t)32 * 8 * 4)
#define OFF_MPHI  (OFF_PSPSI + (size_t)32 * 8 * 4)
#define OFF_ISPHI (OFF_MPHI  + (size_t)32 * 64 * 4)
#define OFF_MPSI  (OFF_ISPHI + (size_t)32 * 64 * 4)
#define OFF_ISPSI (OFF_MPSI  + (size_t)32 * 4)
#define OFF_PRI   (OFF_ISPSI + (size_t)32 * 4)               // partial re/im [32][8][64][2]

// K0: pack weights into GEMM-friendly layout
// wpk[k][n]: n<64 -> PHI_r[k][n], n>=64 -> PHI_theta[k][n-64]; psw[k][{0,1}] = PSI_r[k], PSI_theta[k]
__global__ void k0_pack(const float* __restrict__ psi_r, const float* __restrict__ psi_t,
                        const float* __restrict__ phi_r, const float* __restrict__ phi_t,
                        float* __restrict__ wpk, float* __restrict__ psw) {
    int k = blockIdx.x;          // 0..511
    int n = threadIdx.x;         // 0..63
    wpk[k * 128 + n]      = phi_r[k * 64 + n];
    wpk[k * 128 + 64 + n] = phi_t[k * 64 + n];
    if (n == 0) {
        psw[k * 2 + 0] = psi_r[k];
        psw[k * 2 + 1] = psi_t[k];
    }
}

// K1: z = x @ W  (M=131072, N=128 phi + 2 psi, K=512), fp32 VALU GEMM
// BM=128, BN=128, BK=32; 256 threads; 8x8 register tile split as 2x(4) halves
// to keep LDS b128 reads at <=2-way bank aliasing (free per m136).
__global__ __launch_bounds__(256) void k1_gemm(const float* __restrict__ x,
                                               const float* __restrict__ wpk,
                                               const float* __restrict__ psw_g,
                                               float* __restrict__ zphi,
                                               float* __restrict__ zpsi) {
    __shared__ float xs[32][128];    // [k][m] transposed x tile
    __shared__ float wsh[32][128];   // [k][n] W tile
    __shared__ float pswl[32][2];

    const int t  = threadIdx.x;
    const int tx = t & 15;           // n-group
    const int ty = t >> 4;           // m-group
    const int r0 = blockIdx.x * 128;

    float acc[2][4][2][4];
    #pragma unroll
    for (int ih = 0; ih < 2; ++ih)
        #pragma unroll
        for (int i = 0; i < 4; ++i)
            #pragma unroll
            for (int jh = 0; jh < 2; ++jh)
                #pragma unroll
                for (int j = 0; j < 4; ++j) acc[ih][i][jh][j] = 0.f;

    float pacc = 0.f;
    const int rp = t & 127;          // psi row
    const int cp = t >> 7;           // psi col (0/1)

    for (int kt = 0; kt < 512; kt += 32) {
        __syncthreads();
        // stage x tile: 128 rows x 32 k -> transpose into xs[k][m]
        {
            const int m  = t >> 1;
            const int ks = (t & 1) * 16;
            const float* src = x + (size_t)(r0 + m) * 512 + kt + ks;
            float4 v0 = ((const float4*)src)[0];
            float4 v1 = ((const float4*)src)[1];
            float4 v2 = ((const float4*)src)[2];
            float4 v3 = ((const float4*)src)[3];
            xs[ks + 0][m] = v0.x; xs[ks + 1][m] = v0.y; xs[ks + 2][m] = v0.z; xs[ks + 3][m] = v0.w;
            xs[ks + 4][m] = v1.x; xs[ks + 5][m] = v1.y; xs[ks + 6][m] = v1.z; xs[ks + 7][m] = v1.w;
            xs[ks + 8][m] = v2.x; xs[ks + 9][m] = v2.y; xs[ks +10][m] = v2.z; xs[ks +11][m] = v2.w;
            xs[ks +12][m] = v3.x; xs[ks +13][m] = v3.y; xs[ks +14][m] = v3.z; xs[ks +15][m] = v3.w;
        }
        // stage W tile: 32 k x 128 n (contiguous b128 writes)
        {
            const int kk = t >> 3;
            const int ns = (t & 7) * 16;
            const float* src = wpk + (size_t)(kt + kk) * 128 + ns;
            float4 v0 = ((const float4*)src)[0];
            float4 v1 = ((const float4*)src)[1];
            float4 v2 = ((const float4*)src)[2];
            float4 v3 = ((const float4*)src)[3];
            float* dst = &wsh[kk][ns];
            ((float4*)dst)[0] = v0; ((float4*)dst)[1] = v1;
            ((float4*)dst)[2] = v2; ((float4*)dst)[3] = v3;
        }
        if (t < 32) {
            pswl[t][0] = psw_g[(kt + t) * 2 + 0];
            pswl[t][1] = psw_g[(kt + t) * 2 + 1];
        }
        __syncthreads();

        #pragma unroll 8
        for (int k = 0; k < 32; ++k) {
            float4 a0 = *(const float4*)&xs[k][ty * 4];
            float4 a1 = *(const float4*)&xs[k][64 + ty * 4];
            float4 b0 = *(const float4*)&wsh[k][tx * 4];
            float4 b1 = *(const float4*)&wsh[k][64 + tx * 4];
            float av[2][4] = {{a0.x, a0.y, a0.z, a0.w}, {a1.x, a1.y, a1.z, a1.w}};
            float bv[2][4] = {{b0.x, b0.y, b0.z, b0.w}, {b1.x, b1.y, b1.z, b1.w}};
            #pragma unroll
            for (int ih = 0; ih < 2; ++ih)
                #pragma unroll
                for (int i = 0; i < 4; ++i)
                    #pragma unroll
                    for (int jh = 0; jh < 2; ++jh)
                        #pragma unroll
                        for (int j = 0; j < 4; ++j)
                            acc[ih][i][jh][j] += av[ih][i] * bv[jh][j];
            pacc += xs[k][rp] * pswl[k][cp];
        }
    }

    // write z phi tile
    #pragma unroll
    for (int ih = 0; ih < 2; ++ih)
        #pragma unroll
        for (int i = 0; i < 4; ++i) {
            const int row = r0 + ih * 64 + ty * 4 + i;
            #pragma unroll
            for (int jh = 0; jh < 2; ++jh) {
                float4 v = make_float4(acc[ih][i][jh][0], acc[ih][i][jh][1],
                                       acc[ih][i][jh][2], acc[ih][i][jh][3]);
                *(float4*)&zphi[(size_t)row * 128 + jh * 64 + tx * 4] = v;
            }
        }
    zpsi[(size_t)(r0 + rp) * 2 + cp] = pacc;
}

// K2: per-(b, L-chunk) partial softmax stats (online max/sumexp)
__global__ __launch_bounds__(256) void k2_stats(const float* __restrict__ zphi,
                                                const float* __restrict__ zpsi,
                                                float* __restrict__ pmphi, float* __restrict__ psphi,
                                                float* __restrict__ pmpsi, float* __restrict__ pspsi) {
    const int b = blockIdx.x, ch = blockIdx.y;
    const int t = threadIdx.x, c = t & 63, q = t >> 6;
    __shared__ float sm[256], ss[256];
    const int base = b * L_ + ch * 512;

    float m = -3.4e38f, s = 0.f;
    for (int li = q; li < 512; li += 4) {
        float z = zphi[(size_t)(base + li) * 128 + c];
        float nm = fmaxf(m, z);
        s = s * expf(m - nm) + expf(z - nm);
        m = nm;
    }
    sm[t] = m; ss[t] = s;
    __syncthreads();
    if (q == 0) {
        float M = sm[t], S = ss[t];
        for (int qq = 1; qq < 4; ++qq) {
            float m2 = sm[qq * 64 + c], s2 = ss[qq * 64 + c];
            float nm = fmaxf(M, m2);
            S = S * expf(M - nm) + s2 * expf(m2 - nm);
            M = nm;
        }
        pmphi[(b * 8 + ch) * 64 + c] = M;
        psphi[(b * 8 + ch) * 64 + c] = S;
    }
    __syncthreads();
    if (t < 4) {
        float mp = -3.4e38f, sp = 0.f;
        for (int li = t; li < 512; li += 4) {
            float z = zpsi[(size_t)(base + li) * 2];
            float nm = fmaxf(mp, z);
            sp = sp * expf(mp - nm) + expf(z - nm);
            mp = nm;
        }
        sm[t] = mp; ss[t] = sp;
    }
    __syncthreads();
    if (t == 0) {
        float M = sm[0], S = ss[0];
        for (int qq = 1; qq < 4; ++qq) {
            float nm = fmaxf(M, sm[qq]);
            S = S * expf(M - nm) + ss[qq] * expf(sm[qq] - nm);
            M = nm;
        }
        pmpsi[b * 8 + ch] = M;
        pspsi[b * 8 + ch] = S;
    }
}

// K3: combine 8 chunk partials -> final max + 1/sqrt(sumexp)
__global__ void k3_final(const float* __restrict__ pmphi, const float* __restrict__ psphi,
                         const float* __restrict__ pmpsi, const float* __restrict__ pspsi,
                         float* __restrict__ mphi, float* __restrict__ isphi,
                         float* __restrict__ mpsi, float* __restrict__ ispsi) {
    const int b = blockIdx.x, t = threadIdx.x;
    if (t < 64) {
        float M = -3.4e38f, S = 0.f;
        for (int ch = 0; ch < 8; ++ch) {
            float m2 = pmphi[(b * 8 + ch) * 64 + t], s2 = psphi[(b * 8 + ch) * 64 + t];
            float nm = fmaxf(M, m2);
            S = S * expf(M - nm) + s2 * expf(m2 - nm);
            M = nm;
        }
        mphi[b * 64 + t] = M;
        isphi[b * 64 + t] = 1.0f / sqrtf(S);
    } else if (t == 64) {
        float M = -3.4e38f, S = 0.f;
        for (int ch = 0; ch < 8; ++ch) {
            float m2 = pmpsi[b * 8 + ch], s2 = pspsi[b * 8 + ch];
            float nm = fmaxf(M, m2);
            S = S * expf(M - nm) + s2 * expf(m2 - nm);
            M = nm;
        }
        mpsi[b] = M;
        ispsi[b] = 1.0f / sqrtf(S);
    }
}

// K4: weighted trig reduction over L. psi per-(b,l) values computed once into LDS
// (kills the x64 transcendental redundancy), then 64 states x 4 l-lanes reduce.
__global__ __launch_bounds__(256) void k4_reduce(const float* __restrict__ zphi,
                                                 const float* __restrict__ zpsi,
                                                 const float* __restrict__ mphi, const float* __restrict__ isphi,
                                                 const float* __restrict__ mpsi, const float* __restrict__ ispsi,
                                                 const float* __restrict__ psi_tb_p,
                                                 const float* __restrict__ phi_tb_p,
                                                 float* __restrict__ pri) {
    const int b = blockIdx.x, ch = blockIdx.y, t = threadIdx.x;
    __shared__ float als[512], bls[512];
    const int base = b * L_ + ch * 512;
    const float psi_tb = psi_tb_p[0], phi_tb = phi_tb_p[0];

    // phase 1: psi amplitude-phase per l
    {
        const float mps = mpsi[b], isp = ispsi[b];
        for (int li = t; li < 512; li += 256) {
            float2 zp = *(const float2*)&zpsi[(size_t)(base + li) * 2];
            float e = expf((zp.x - mps) * 0.5f) * isp;
            float ang = PI_F * (1.0f + tanhf(zp.y + psi_tb));
            float sA, cA;
            sincosf(ang, &sA, &cA);
            als[li] = e * cA;
            bls[li] = e * sA;
        }
    }
    __syncthreads();

    // phase 2: per-state weighted reduction
    const int c = t & 63, q = t >> 6;
    const float mf = mphi[b * 64 + c], isf = isphi[b * 64 + c];
    float re = 0.f, im = 0.f;
    for (int li = q; li < 512; li += 4) {
        const size_t idx = (size_t)(base + li) * 128 + c;
        float zr = zphi[idx];
        float zt = zphi[idx + 64];
        float e = expf((zr - mf) * 0.5f) * isf;
        float ang = -PI_F * (1.0f + PI_F * tanhf(zt + phi_tb));
        float sB, cB;
        sincosf(ang, &sB, &cB);
        float u = e * cB, v = e * sB;
        float a_ = als[li], c_ = bls[li];
        re += a_ * u + c_ * v;   // cos(a-b) identity
        im += c_ * u - a_ * v;   // sin(a-b) identity
    }
    __syncthreads();
    als[t] = re; bls[t] = im;
    __syncthreads();
    if (q == 0) {
        for (int qq = 1; qq < 4; ++qq) { re += als[qq * 64 + c]; im += bls[qq * 64 + c]; }
        pri[((size_t)(b * 8 + ch) * 64 + c) * 2 + 0] = re;
        pri[((size_t)(b * 8 + ch) * 64 + c) * 2 + 1] = im;
    }
}

// K5: combine chunk partials -> collapse -> output GEMM [32,64]@[64,512] + bias
__global__ __launch_bounds__(512) void k5_out(const float* __restrict__ pri,
                                              const float* __restrict__ Smat,
                                              const float* __restrict__ sb_p,
                                              float* __restrict__ out) {
    const int b = blockIdx.x, t = threadIdx.x;
    __shared__ float cls[64];
    if (t < 64) {
        float re = 0.f, im = 0.f;
        for (int ch = 0; ch < 8; ++ch) {
            re += pri[((size_t)(b * 8 + ch) * 64 + t) * 2 + 0];
            im += pri[((size_t)(b * 8 + ch) * 64 + t) * 2 + 1];
        }
        cls[t] = re * re + im * im;
    }
    __syncthreads();
    float acc = sb_p[0];
    #pragma unroll 8
    for (int n = 0; n < 64; ++n) acc += cls[n] * Smat[n * UNITS + t];
    out[(size_t)b * UNITS + t] = acc;
}

extern "C" void kernel_launch(void* const* d_in, const int* in_sizes, int n_in,
                              void* d_out, int out_size, void* d_ws, size_t ws_size,
                              hipStream_t stream) {
    const float* x      = (const float*)d_in[0];
    const float* psi_r  = (const float*)d_in[1];
    const float* psi_t  = (const float*)d_in[2];
    const float* psi_tb = (const float*)d_in[3];
    const float* phi_r  = (const float*)d_in[4];
    const float* phi_t  = (const float*)d_in[5];
    const float* phi_tb = (const float*)d_in[6];
    const float* Smat   = (const float*)d_in[7];
    const float* sb     = (const float*)d_in[8];
    float* out = (float*)d_out;

    char* ws = (char*)d_ws;
    float* wpk   = (float*)(ws + OFF_WPK);
    float* psw   = (float*)(ws + OFF_PSW);
    float* zphi  = (float*)(ws + OFF_ZPHI);
    float* zpsi  = (float*)(ws + OFF_ZPSI);
    float* pmphi = (float*)(ws + OFF_PMPHI);
    float* psphi = (float*)(ws + OFF_PSPHI);
    float* pmpsi = (float*)(ws + OFF_PMPSI);
    float* pspsi = (float*)(ws + OFF_PSPSI);
    float* mphi  = (float*)(ws + OFF_MPHI);
    float* isphi = (float*)(ws + OFF_ISPHI);
    float* mpsi  = (float*)(ws + OFF_MPSI);
    float* ispsi = (float*)(ws + OFF_ISPSI);
    float* pri   = (float*)(ws + OFF_PRI);

    k0_pack<<<512, 64, 0, stream>>>(psi_r, psi_t, phi_r, phi_t, wpk, psw);
    k1_gemm<<<ROWS / 128, 256, 0, stream>>>(x, wpk, psw, zphi, zpsi);
    k2_stats<<<dim3(B_, 8), 256, 0, stream>>>(zphi, zpsi, pmphi, psphi, pmpsi, pspsi);
    k3_final<<<B_, 128, 0, stream>>>(pmphi, psphi, pmpsi, pspsi, mphi, isphi, mpsi, ispsi);
    k4_reduce<<<dim3(B_, 8), 256, 0, stream>>>(zphi, zpsi, mphi, isphi, mpsi, ispsi,
                                               psi_tb, phi_tb, pri);
    k5_out<<<B_, 512, 0, stream>>>(pri, Smat, sb, out);
}

// Round 2
// 141.235 us; speedup vs baseline: 2.5754x; 2.5754x over previous
//
#include <hip/hip_runtime.h>
#include <math.h>

#define B_    32
#define L_    4096
#define D_    512
#define NST   64
#define UNITS 512
#define ROWS  (B_ * L_)          // 131072
#define PI_F  3.14159265358979323846f
#define ROWU  20                 // uints per 32-k LDS row (80 B: 5*r mod 8 bank spread)

typedef __attribute__((ext_vector_type(8))) short short8;
typedef __attribute__((ext_vector_type(4))) float f32x4;

__device__ inline ushort f2bf(float f) {
    uint u = __float_as_uint(f);
    return (ushort)((u + 0x7fffu + ((u >> 16) & 1u)) >> 16);   // RNE
}
__device__ inline float bf2f(ushort h) { return __uint_as_float(((uint)h) << 16); }

__device__ inline void onl(float& m, float& s, float m2, float s2) {
    float nm = fmaxf(m, m2);
    s = s * expf(m - nm) + s2 * expf(m2 - nm);
    m = nm;
}

// ---------------- workspace layout (bytes) ----------------
#define OFF_WHT   ((size_t)0)                                   // [128][512] bf16 hi (W^T)
#define OFF_WLT   (OFF_WHT   + (size_t)128 * 512 * 2)           // [128][512] bf16 lo
#define OFF_PSW   (OFF_WLT   + (size_t)128 * 512 * 2)           // [512][2] f32 psi weights
#define OFF_ZPHI  (OFF_PSW   + (size_t)512 * 2 * 4)             // [ROWS][128] f32
#define OFF_ZPSI  (OFF_ZPHI  + (size_t)ROWS * 128 * 4)          // [ROWS][2] f32
#define OFF_PMPHI (OFF_ZPSI  + (size_t)ROWS * 2 * 4)            // [1024][64]
#define OFF_PSPHI (OFF_PMPHI + (size_t)1024 * 64 * 4)
#define OFF_PMPSI (OFF_PSPHI + (size_t)1024 * 64 * 4)           // [1024]
#define OFF_PSPSI (OFF_PMPSI + (size_t)1024 * 4)
#define OFF_MPHI  (OFF_PSPSI + (size_t)1024 * 4)                // [32][64]
#define OFF_ISPHI (OFF_MPHI  + (size_t)32 * 64 * 4)
#define OFF_MPSI  (OFF_ISPHI + (size_t)32 * 64 * 4)             // [32]
#define OFF_ISPSI (OFF_MPSI  + (size_t)32 * 4)
#define OFF_PRI   OFF_PMPHI   // [32][32][64][2] aliases pm/ps-phi (dead after k2_final)

// K0: split weights into bf16 hi/lo, transposed [n][k] for MFMA B-operand reads
__global__ void k0_pack(const float* __restrict__ psi_r, const float* __restrict__ psi_t,
                        const float* __restrict__ phi_r, const float* __restrict__ phi_t,
                        ushort* __restrict__ wht, ushort* __restrict__ wlt,
                        float* __restrict__ psw) {
    const int k = blockIdx.x;     // 0..511
    const int n = threadIdx.x;    // 0..63
    float w0 = phi_r[k * 64 + n];
    float w1 = phi_t[k * 64 + n];
    ushort h0 = f2bf(w0), h1 = f2bf(w1);
    wht[(size_t)n * 512 + k]        = h0;
    wht[(size_t)(64 + n) * 512 + k] = h1;
    wlt[(size_t)n * 512 + k]        = f2bf(w0 - bf2f(h0));
    wlt[(size_t)(64 + n) * 512 + k] = f2bf(w1 - bf2f(h1));
    if (n == 0) { psw[k * 2 + 0] = psi_r[k]; psw[k * 2 + 1] = psi_t[k]; }
}

// K1: z = x @ W via 3-pass split-bf16 MFMA (hi*hi + hi*lo + lo*hi), fp32 accum.
// 128x128 tile, BK=32, 4 waves each 64x64 (4x4 frags of 16x16x32).
// psi (2 cols) fused into staging loads on VALU. Per-block softmax partials fused.
__global__ __launch_bounds__(256) void k1_gemm(
        const float* __restrict__ x, const uint* __restrict__ wht, const uint* __restrict__ wlt,
        const float* __restrict__ psw_g,
        float* __restrict__ zphi, float* __restrict__ zpsi,
        float* __restrict__ pmphi, float* __restrict__ psphi,
        float* __restrict__ pmpsi, float* __restrict__ pspsi) {
    __shared__ uint Ah[128 * ROWU], Al[128 * ROWU];    // x tile hi/lo, [row][40 bf16] pad 80B
    __shared__ uint Bh[128 * ROWU], Bl[128 * ROWU];    // W^T tile hi/lo
    __shared__ __align__(16) float2 pswl[512];
    __shared__ float stat_m[2][64], stat_s[2][64];
    __shared__ float psr[128];

    const int t    = threadIdx.x;
    const int lane = t & 63;
    const int w = t >> 6, wr = w >> 1, wc = w & 1;
    const int r0 = blockIdx.x * 128;
    const int hi16 = lane >> 4, lo16 = lane & 15;

    ((float4*)pswl)[t] = ((const float4*)psw_g)[t];    // 1024 floats = 256 float4

    f32x4 acc[4][4];
    #pragma unroll
    for (int i = 0; i < 4; ++i)
        #pragma unroll
        for (int j = 0; j < 4; ++j) acc[i][j] = (f32x4)0.f;

    float paccr[4] = {0.f, 0.f, 0.f, 0.f}, pacct[4] = {0.f, 0.f, 0.f, 0.f};
    const int xrow = t >> 3, xj = t & 7;   // x stage: row (t>>3)+32p, float4 idx xj
    const int wn = t >> 2, jw = t & 3;     // W stage: row (t>>2)+64p, uint4 idx jw

    __syncthreads();

    for (int kt = 0; kt < 512; kt += 32) {
        float4 xv[4];
        #pragma unroll
        for (int p = 0; p < 4; ++p)
            xv[p] = *(const float4*)&x[(size_t)(r0 + xrow + 32 * p) * 512 + kt + xj * 4];

        // psi partial dots (full fp32 precision)
        #pragma unroll
        for (int e = 0; e < 4; ++e) {
            float2 ww = pswl[kt + xj * 4 + e];
            #pragma unroll
            for (int p = 0; p < 4; ++p) {
                float xe = ((const float*)&xv[p])[e];
                paccr[p] = fmaf(xe, ww.x, paccr[p]);
                pacct[p] = fmaf(xe, ww.y, pacct[p]);
            }
        }

        // split fp32 -> bf16 hi + lo, stage A tiles
        #pragma unroll
        for (int p = 0; p < 4; ++p) {
            const float* xe = (const float*)&xv[p];
            ushort a0 = f2bf(xe[0]), a1 = f2bf(xe[1]), a2 = f2bf(xe[2]), a3 = f2bf(xe[3]);
            ushort b0 = f2bf(xe[0] - bf2f(a0)), b1 = f2bf(xe[1] - bf2f(a1));
            ushort b2 = f2bf(xe[2] - bf2f(a2)), b3 = f2bf(xe[3] - bf2f(a3));
            uint2 hh = make_uint2((uint)a0 | ((uint)a1 << 16), (uint)a2 | ((uint)a3 << 16));
            uint2 ll = make_uint2((uint)b0 | ((uint)b1 << 16), (uint)b2 | ((uint)b3 << 16));
            const int off = (xrow + 32 * p) * ROWU + xj * 2;
            *(uint2*)&Ah[off] = hh;
            *(uint2*)&Al[off] = ll;
        }

        // stage B tiles (already bf16 hi/lo in ws)
        #pragma unroll
        for (int p = 0; p < 2; ++p) {
            const int n = wn + 64 * p;
            const size_t gi = (size_t)n * 256 + (kt >> 1) + jw * 4;
            uint4 vh = *(const uint4*)&wht[gi];
            uint4 vl = *(const uint4*)&wlt[gi];
            *(uint4*)&Bh[n * ROWU + jw * 4] = vh;
            *(uint4*)&Bl[n * ROWU + jw * 4] = vl;
        }
        __syncthreads();

        short8 ahf[4], alf[4];
        #pragma unroll
        for (int mi = 0; mi < 4; ++mi) {
            const int off = (wr * 64 + mi * 16 + lo16) * ROWU + hi16 * 4;
            ahf[mi] = *(const short8*)&Ah[off];
            alf[mi] = *(const short8*)&Al[off];
        }
        #pragma unroll
        for (int nj = 0; nj < 4; ++nj) {
            const int off = (wc * 64 + nj * 16 + lo16) * ROWU + hi16 * 4;
            short8 bhf = *(const short8*)&Bh[off];
            short8 blf = *(const short8*)&Bl[off];
            #pragma unroll
            for (int mi = 0; mi < 4; ++mi) {
                acc[mi][nj] = __builtin_amdgcn_mfma_f32_16x16x32_bf16(ahf[mi], bhf, acc[mi][nj], 0, 0, 0);
                acc[mi][nj] = __builtin_amdgcn_mfma_f32_16x16x32_bf16(ahf[mi], blf, acc[mi][nj], 0, 0, 0);
                acc[mi][nj] = __builtin_amdgcn_mfma_f32_16x16x32_bf16(alf[mi], bhf, acc[mi][nj], 0, 0, 0);
            }
        }
        __syncthreads();
    }

    // ---- epilogue: z stores + fused per-block softmax partials ----
    float smv[4], ssv[4];
    #pragma unroll
    for (int nj = 0; nj < 4; ++nj) {
        const int colg = wc * 64 + nj * 16 + lo16;
        float m = -3.4e38f, s = 0.f;
        #pragma unroll
        for (int mi = 0; mi < 4; ++mi) {
            const int rowg = r0 + wr * 64 + mi * 16 + hi16 * 4;
            #pragma unroll
            for (int r = 0; r < 4; ++r) {
                float z = acc[mi][nj][r];
                zphi[(size_t)(rowg + r) * 128 + colg] = z;
                float nm = fmaxf(m, z);
                s = s * expf(m - nm) + expf(z - nm);
                m = nm;
            }
        }
        smv[nj] = m; ssv[nj] = s;
    }
    if (wc == 0) {   // softmax stats only for the r-columns (0..63)
        #pragma unroll
        for (int nj = 0; nj < 4; ++nj) {
            float m = smv[nj], s = ssv[nj];
            #pragma unroll
            for (int off = 16; off <= 32; off <<= 1) {
                float m2 = __shfl_xor(m, off);
                float s2 = __shfl_xor(s, off);
                onl(m, s, m2, s2);
            }
            if (lane < 16) { stat_m[wr][nj * 16 + lo16] = m; stat_s[wr][nj * 16 + lo16] = s; }
        }
    }
    // psi: reduce the 8 k-segment partials per row (lanes xor 1,2,4)
    #pragma unroll
    for (int p = 0; p < 4; ++p) {
        #pragma unroll
        for (int off = 1; off <= 4; off <<= 1) {
            paccr[p] += __shfl_xor(paccr[p], off);
            pacct[p] += __shfl_xor(pacct[p], off);
        }
    }
    if (xj == 0) {
        #pragma unroll
        for (int p = 0; p < 4; ++p) {
            const int row = xrow + 32 * p;
            ((float2*)zpsi)[r0 + row] = make_float2(paccr[p], pacct[p]);
            psr[row] = paccr[p];
        }
    }
    __syncthreads();
    if (t < 64) {
        float M = stat_m[0][t], S = stat_s[0][t];
        onl(M, S, stat_m[1][t], stat_s[1][t]);
        pmphi[(size_t)blockIdx.x * 64 + t] = M;
        psphi[(size_t)blockIdx.x * 64 + t] = S;
    } else if (t < 128) {
        const int i = t - 64;
        float a = psr[i], bb = psr[i + 64];
        float M = fmaxf(a, bb);
        float S = expf(a - M) + expf(bb - M);
        #pragma unroll
        for (int off = 1; off <= 32; off <<= 1) {
            float m2 = __shfl_xor(M, off);
            float s2 = __shfl_xor(S, off);
            onl(M, S, m2, s2);
        }
        if (i == 0) { pmpsi[blockIdx.x] = M; pspsi[blockIdx.x] = S; }
    }
}

// K2: combine 32 per-block partials -> final max + 1/sqrt(sumexp)
__global__ void k2_final(const float* __restrict__ pmphi, const float* __restrict__ psphi,
                         const float* __restrict__ pmpsi, const float* __restrict__ pspsi,
                         float* __restrict__ mphi, float* __restrict__ isphi,
                         float* __restrict__ mpsi, float* __restrict__ ispsi) {
    const int b = blockIdx.x, t = threadIdx.x;
    if (t < 64) {
        float M = -3.4e38f, S = 0.f;
        for (int ch = 0; ch < 32; ++ch)
            onl(M, S, pmphi[(size_t)(b * 32 + ch) * 64 + t], psphi[(size_t)(b * 32 + ch) * 64 + t]);
        mphi[b * 64 + t] = M;
        isphi[b * 64 + t] = 1.0f / sqrtf(S);
    } else if (t == 64) {
        float M = -3.4e38f, S = 0.f;
        for (int ch = 0; ch < 32; ++ch)
            onl(M, S, pmpsi[b * 32 + ch], pspsi[b * 32 + ch]);
        mpsi[b] = M;
        ispsi[b] = 1.0f / sqrtf(S);
    }
}

// K4: weighted trig reduction. 1024 blocks (4/CU) of 128 rows; float4 z loads;
// psi per-(b,l) sin/cos computed once into LDS (angle-subtraction identity).
__global__ __launch_bounds__(256) void k4_reduce(
        const float* __restrict__ zphi, const float* __restrict__ zpsi,
        const float* __restrict__ mphi, const float* __restrict__ isphi,
        const float* __restrict__ mpsi, const float* __restrict__ ispsi,
        const float* __restrict__ psi_tb_p, const float* __restrict__ phi_tb_p,
        float* __restrict__ pri) {
    const int b = blockIdx.x, ch = blockIdx.y, t = threadIdx.x;
    const int base = b * L_ + ch * 128;
    __shared__ float als[128], bls[128];
    __shared__ float red[16][64][2];
    const float phi_tb = phi_tb_p[0];

    if (t < 128) {
        const float psi_tb = psi_tb_p[0];
        float2 zp = ((const float2*)zpsi)[base + t];
        float e = expf((zp.x - mpsi[b]) * 0.5f) * ispsi[b];
        float ang = PI_F * (1.0f + tanhf(zp.y + psi_tb));
        float sA, cA;
        sincosf(ang, &sA, &cA);
        als[t] = e * cA;
        bls[t] = e * sA;
    }
    __syncthreads();

    const int c4 = t & 15, q = t >> 4;
    float4 mf = *(const float4*)&mphi[b * 64 + c4 * 4];
    float4 isf = *(const float4*)&isphi[b * 64 + c4 * 4];
    float re[4] = {0.f, 0.f, 0.f, 0.f}, im[4] = {0.f, 0.f, 0.f, 0.f};

    for (int li = q; li < 128; li += 16) {
        float4 zr = *(const float4*)&zphi[(size_t)(base + li) * 128 + c4 * 4];
        float4 zt = *(const float4*)&zphi[(size_t)(base + li) * 128 + 64 + c4 * 4];
        float a_ = als[li], b_ = bls[li];
        #pragma unroll
        for (int e = 0; e < 4; ++e) {
            float zre = ((const float*)&zr)[e];
            float zte = ((const float*)&zt)[e];
            float ee = expf((zre - ((const float*)&mf)[e]) * 0.5f) * ((const float*)&isf)[e];
            float ang = -PI_F * (1.0f + PI_F * tanhf(zte + phi_tb));
            float sB, cB;
            sincosf(ang, &sB, &cB);
            float u = ee * cB, v = ee * sB;
            re[e] += a_ * u + b_ * v;
            im[e] += b_ * u - a_ * v;
        }
    }
    #pragma unroll
    for (int e = 0; e < 4; ++e) { red[q][c4 * 4 + e][0] = re[e]; red[q][c4 * 4 + e][1] = im[e]; }
    __syncthreads();
    if (t < 128) {
        const int col = t & 63, ri = t >> 6;
        float sum = 0.f;
        #pragma unroll
        for (int qq = 0; qq < 16; ++qq) sum += red[qq][col][ri];
        pri[((size_t)(b * 32 + ch) * 64 + col) * 2 + ri] = sum;
    }
}

// K5: combine chunk partials -> collapse -> output GEMM [32,64]@[64,512] + bias
__global__ __launch_bounds__(512) void k5_out(const float* __restrict__ pri,
                                              const float* __restrict__ Smat,
                                              const float* __restrict__ sb_p,
                                              float* __restrict__ out) {
    const int b = blockIdx.x, t = threadIdx.x;
    __shared__ float cls[64];
    if (t < 64) {
        float re = 0.f, im = 0.f;
        for (int ch = 0; ch < 32; ++ch) {
            re += pri[((size_t)(b * 32 + ch) * 64 + t) * 2 + 0];
            im += pri[((size_t)(b * 32 + ch) * 64 + t) * 2 + 1];
        }
        cls[t] = re * re + im * im;
    }
    __syncthreads();
    float acc = sb_p[0];
    #pragma unroll 8
    for (int n = 0; n < 64; ++n) acc = fmaf(cls[n], Smat[n * UNITS + t], acc);
    out[(size_t)b * UNITS + t] = acc;
}

extern "C" void kernel_launch(void* const* d_in, const int* in_sizes, int n_in,
                              void* d_out, int out_size, void* d_ws, size_t ws_size,
                              hipStream_t stream) {
    const float* x      = (const float*)d_in[0];
    const float* psi_r  = (const float*)d_in[1];
    const float* psi_t  = (const float*)d_in[2];
    const float* psi_tb = (const float*)d_in[3];
    const float* phi_r  = (const float*)d_in[4];
    const float* phi_t  = (const float*)d_in[5];
    const float* phi_tb = (const float*)d_in[6];
    const float* Smat   = (const float*)d_in[7];
    const float* sb     = (const float*)d_in[8];
    float* out = (float*)d_out;

    char* ws = (char*)d_ws;
    ushort* wht  = (ushort*)(ws + OFF_WHT);
    ushort* wlt  = (ushort*)(ws + OFF_WLT);
    float* psw   = (float*)(ws + OFF_PSW);
    float* zphi  = (float*)(ws + OFF_ZPHI);
    float* zpsi  = (float*)(ws + OFF_ZPSI);
    float* pmphi = (float*)(ws + OFF_PMPHI);
    float* psphi = (float*)(ws + OFF_PSPHI);
    float* pmpsi = (float*)(ws + OFF_PMPSI);
    float* pspsi = (float*)(ws + OFF_PSPSI);
    float* mphi  = (float*)(ws + OFF_MPHI);
    float* isphi = (float*)(ws + OFF_ISPHI);
    float* mpsi  = (float*)(ws + OFF_MPSI);
    float* ispsi = (float*)(ws + OFF_ISPSI);
    float* pri   = (float*)(ws + OFF_PRI);

    k0_pack<<<512, 64, 0, stream>>>(psi_r, psi_t, phi_r, phi_t, wht, wlt, psw);
    k1_gemm<<<ROWS / 128, 256, 0, stream>>>(x, (const uint*)wht, (const uint*)wlt, psw,
                                            zphi, zpsi, pmphi, psphi, pmpsi, pspsi);
    k2_final<<<B_, 128, 0, stream>>>(pmphi, psphi, pmpsi, pspsi, mphi, isphi, mpsi, ispsi);
    k4_reduce<<<dim3(B_, 32), 256, 0, stream>>>(zphi, zpsi, mphi, isphi, mpsi, ispsi,
                                                psi_tb, phi_tb, pri);
    k5_out<<<B_, 512, 0, stream>>>(pri, Smat, sb, out);
}